// Round 1
// baseline (1121.354 us; speedup 1.0000x reference)
//
#include <hip/hip_runtime.h>

// PINN jet-propagation kernel.
// One thread = one sample. 3rd-order forward-mode jets (u, u', u'', u''')
// through 5 tanh layers (width 50), then head:
//   out[n][j] = u0[j] + sum_k (dt*f_k) * M[k][j],  f = -l1*u0*u1 - l2*u3
//   M[k][j] = beta[k] - alpha[j][k]   (dt folded into M at prep time)

constexpr int WID = 50;    // hidden width
constexpr int Q   = 100;   // outputs
constexpr int BLK = 256;   // threads per block
constexpr int NS  = 53;    // per-thread LDS stride in dwords (gcd(53,32)=1 -> conflict-free)

__device__ __forceinline__ float ftanh(float z) {
    // tanh(z) = 1 - 2/(exp(2z)+1); exact at +-inf saturation, ~1e-7 abs err.
    float e = __expf(2.0f * z);
    float r = __builtin_amdgcn_rcpf(e + 1.0f);
    return fmaf(-2.0f, r, 1.0f);
}

// One jet's linear transform, in place: stash A (h_k) to private LDS, rebuild
// A as z_k = W^T h_k (+ b if BIAS). Weights are wave-uniform -> s_load.
template<bool BIAS>
__device__ __forceinline__ void zphase(float (&A)[WID], const float* __restrict__ Wt,
                                       const float* __restrict__ b, float* __restrict__ myl)
{
#pragma unroll
    for (int j = 0; j < WID; ++j) myl[j] = A[j];
#pragma unroll
    for (int i = 0; i < WID; ++i) A[i] = BIAS ? b[i] : 0.0f;
#pragma unroll 1
    for (int j = 0; j < WID; ++j) {
        float hj = myl[j];
        const float* wr = Wt + j * WID;
#pragma unroll
        for (int i = 0; i < WID; ++i) A[i] = fmaf(wr[i], hj, A[i]);
    }
}

__device__ __forceinline__ void layer(const float* __restrict__ Wt, const float* __restrict__ b,
                                      float (&A0)[WID], float (&A1)[WID],
                                      float (&A2)[WID], float (&A3)[WID],
                                      float* __restrict__ myl)
{
    zphase<true >(A0, Wt, b, myl);
    zphase<false>(A1, Wt, b, myl);
    zphase<false>(A2, Wt, b, myl);
    zphase<false>(A3, Wt, b, myl);
    // tanh jet mixing (Faa di Bruno):
    // t'=s=1-t^2, t''=-2ts, t'''=-2s(3s-2)
#pragma unroll
    for (int i = 0; i < WID; ++i) {
        float z0 = A0[i], z1 = A1[i], z2 = A2[i], z3 = A3[i];
        float t  = ftanh(z0);
        float s  = fmaf(-t, t, 1.0f);
        float c2 = -2.0f * t * s;
        float c3 = -2.0f * s * fmaf(3.0f, s, -2.0f);
        float z1sq = z1 * z1;
        A0[i] = t;
        A1[i] = s * z1;
        A2[i] = fmaf(c2, z1sq, s * z2);
        A3[i] = fmaf(c3, z1sq * z1, fmaf(3.0f * c2, z1 * z2, s * z3));
    }
}

// Output chunk [BASE, BASE+CH): recompute u0,u1,u3,f for all k, accumulate
// dt*f * Mdt row into oa.  u0's diagonal add bounces via private LDS so the
// register array is never dynamically indexed.
template<int BASE, int CH>
__device__ __forceinline__ void head(const float* __restrict__ WT, const float* __restrict__ Mdt,
                                     const float* __restrict__ bout, float l1, float l2,
                                     const float (&A0)[WID], const float (&A1)[WID],
                                     const float (&A3)[WID],
                                     float* __restrict__ myl, float* __restrict__ outp, bool act)
{
    float oa[CH];
#pragma unroll
    for (int j = 0; j < CH; ++j) oa[j] = 0.0f;
#pragma unroll 1
    for (int k = 0; k < Q; ++k) {
        const float* wr = WT + k * WID;
        float u0a = 0.f, u0b = 0.f, u1a = 0.f, u1b = 0.f, u3a = 0.f, u3b = 0.f;
#pragma unroll
        for (int j = 0; j < WID; j += 2) {
            float w0 = wr[j], w1 = wr[j + 1];
            u0a = fmaf(A0[j], w0, u0a); u0b = fmaf(A0[j + 1], w1, u0b);
            u1a = fmaf(A1[j], w0, u1a); u1b = fmaf(A1[j + 1], w1, u1b);
            u3a = fmaf(A3[j], w0, u3a); u3b = fmaf(A3[j + 1], w1, u3b);
        }
        float u0 = u0a + u0b + bout[k];
        float u1 = u1a + u1b;
        float u3 = u3a + u3b;
        float f  = -(l1 * u0) * u1 - l2 * u3;   // dt folded into Mdt
        if (k >= BASE && k < BASE + CH) myl[k - BASE] = u0;
        const float* mr = Mdt + k * Q + BASE;
#pragma unroll
        for (int j = 0; j < CH; ++j) oa[j] = fmaf(f, mr[j], oa[j]);
    }
#pragma unroll
    for (int j = 0; j < CH; ++j) oa[j] += myl[j];
    if (act) {
#pragma unroll
        for (int j = 0; j < CH; j += 4) {
            float4 v = make_float4(oa[j], oa[j + 1], oa[j + 2], oa[j + 3]);
            *reinterpret_cast<float4*>(outp + BASE + j) = v;
        }
    }
}

__global__ __launch_bounds__(BLK) void pinn_prep(const float* __restrict__ alpha,
                                                 const float* __restrict__ beta,
                                                 const float* __restrict__ dtp,
                                                 const float* __restrict__ Wout,
                                                 float* __restrict__ ws)
{
    float dt = dtp[0];
    int i = blockIdx.x * blockDim.x + threadIdx.x;
    if (i < Q * Q) {
        int k = i / Q, j = i % Q;
        ws[i] = dt * (beta[k] - alpha[j * Q + k]);     // Mdt[k][j]
    }
    if (i < Q * WID) {
        int k = i / WID, j = i % WID;
        ws[Q * Q + i] = Wout[j * Q + k];               // WoutT[k][j]
    }
}

__global__ __launch_bounds__(BLK) void pinn_main(
    const float* __restrict__ X, int N,
    const float* __restrict__ W1, const float* __restrict__ b1,
    const float* __restrict__ W2, const float* __restrict__ b2,
    const float* __restrict__ W3, const float* __restrict__ b3,
    const float* __restrict__ W4, const float* __restrict__ b4,
    const float* __restrict__ W5, const float* __restrict__ b5,
    const float* __restrict__ bout,
    const float* __restrict__ l1p, const float* __restrict__ l2p,
    const float* __restrict__ ws,
    float* __restrict__ out)
{
    __shared__ float sl[BLK * NS];
    float* myl = &sl[threadIdx.x * NS];
    int n = blockIdx.x * BLK + threadIdx.x;
    bool act = n < N;
    float x = act ? X[n] : 0.0f;

    float A0[WID], A1[WID], A2[WID], A3[WID];
    // layer 1: input jets (x, 1, 0, 0); z0 = w*x+b, z1 = w, z2 = z3 = 0
#pragma unroll
    for (int i = 0; i < WID; ++i) {
        float w  = W1[i];
        float z0 = fmaf(x, w, b1[i]);
        float t  = ftanh(z0);
        float s  = fmaf(-t, t, 1.0f);
        float c2 = -2.0f * t * s;
        float c3 = -2.0f * s * fmaf(3.0f, s, -2.0f);
        float wsq = w * w;
        A0[i] = t;
        A1[i] = s * w;
        A2[i] = c2 * wsq;
        A3[i] = c3 * wsq * w;
    }

    layer(W2, b2, A0, A1, A2, A3, myl);
    layer(W3, b3, A0, A1, A2, A3, myl);
    layer(W4, b4, A0, A1, A2, A3, myl);
    layer(W5, b5, A0, A1, A2, A3, myl);

    const float* Mdt = ws;
    const float* WT  = ws + Q * Q;
    float l1 = l1p[0];
    float l2 = l2p[0];
    float* outp = out + (size_t)n * Q;

    head< 0, 52>(WT, Mdt, bout, l1, l2, A0, A1, A3, myl, outp, act);
    head<52, 48>(WT, Mdt, bout, l1, l2, A0, A1, A3, myl, outp, act);
}

extern "C" void kernel_launch(void* const* d_in, const int* in_sizes, int n_in,
                              void* d_out, int out_size, void* d_ws, size_t ws_size,
                              hipStream_t stream)
{
    const float* X     = (const float*)d_in[0];
    const float* dt    = (const float*)d_in[1];
    const float* alpha = (const float*)d_in[2];
    const float* beta  = (const float*)d_in[3];
    const float* W1    = (const float*)d_in[4];
    const float* b1    = (const float*)d_in[5];
    const float* W2    = (const float*)d_in[6];
    const float* b2    = (const float*)d_in[7];
    const float* W3    = (const float*)d_in[8];
    const float* b3    = (const float*)d_in[9];
    const float* W4    = (const float*)d_in[10];
    const float* b4    = (const float*)d_in[11];
    const float* W5    = (const float*)d_in[12];
    const float* b5    = (const float*)d_in[13];
    const float* Wout  = (const float*)d_in[14];
    const float* bout  = (const float*)d_in[15];
    const float* l1    = (const float*)d_in[16];
    const float* l2    = (const float*)d_in[17];

    float* ws = (float*)d_ws;
    int N = in_sizes[0];

    pinn_prep<<<40, BLK, 0, stream>>>(alpha, beta, dt, Wout, ws);

    int grid = (N + BLK - 1) / BLK;
    pinn_main<<<grid, BLK, 0, stream>>>(X, N, W1, b1, W2, b2, W3, b3, W4, b4, W5, b5,
                                        bout, l1, l2, ws, (float*)d_out);
}